// Round 4
// baseline (1465.896 us; speedup 1.0000x reference)
//
#include <hip/hip_runtime.h>
#include <hip/hip_bf16.h>

// ---------------------------------------------------------------------------
// QuestionGuidedGraphAttention on MI355X — v5
//
// att_n = segsoftmax( tanh(nodes@W_n + (question@W_nq + b_nq + b_n)[gid]) @ w_nv + b_nv )
// att_e = same for edges.
//
// v5 = v4 hardened (v4 bench died container-side, no counters; v3 = 1263 us):
//  - B ring 4 -> 3 slots (96 KB): total LDS ~98 KB, matching v3's proven
//    footprint. WAR-safe: slot (t+2)%3 last read in step t-1, whose ds_reads
//    complete before any wave passes step t's barrier (lgkmcnt before MFMA).
//  - gsh/zpart init pinned with sched_barrier(0) so its compiler vmcnt(0)
//    drains only the gid load and cannot sink into the DMA issue region
//    (keeps the hand-counted vmcnt queue exact).
// Carried from v4:
//  - A loaded global->reg per wave (rows wave-private; col-waves hit L1);
//    no A LDS staging at all.
//  - ONE raw s_barrier per k-step; B(t+2)/A(t+2) issued after it; steady
//    s_waitcnt vmcnt(8) keeps 8 VMEM (next tile) in flight across barriers.
//  - fp32->bf16 pack via +0x8000 + v_perm_b32 (1.5 VALU/elt).
// ---------------------------------------------------------------------------

typedef __attribute__((ext_vector_type(4))) float  floatx4;
typedef __attribute__((ext_vector_type(8))) short  shortx8;

#define TN_CONST 131072
#define TE_CONST 262144
#define BM 64
#define BK 32
#define NSTEP 16   // 512 / BK

__device__ __forceinline__ unsigned short f2bf(float f) {
    union { float f; unsigned u; } v; v.f = f;
    unsigned u = v.u;
    unsigned r = (u + 0x7FFFu + ((u >> 16) & 1u)) >> 16;   // RNE
    return (unsigned short)r;
}

// pack two f32 -> two bf16 in one dword (round-half-up; ties-only delta vs RNE)
__device__ __forceinline__ unsigned packbf(float lo, float hi) {
    union { float f; unsigned u; } a, b; a.f = lo; b.f = hi;
    return __builtin_amdgcn_perm(b.u + 0x8000u, a.u + 0x8000u, 0x07060302u);
}

__device__ __forceinline__ void gload16(const void* g, void* l) {
    __builtin_amdgcn_global_load_lds((const __attribute__((address_space(1))) void*)g,
                                     (__attribute__((address_space(3))) void*)l,
                                     16, 0, 0);
}

// --- W transpose + bf16 convert, k-window tiled --------------------------
// Wt[(k>>5)][p][k&31] = bf16(W[k][p])   (each 32-k window contiguous: 512*32)
__global__ void prep_wt_kernel(const float* __restrict__ Wn, const float* __restrict__ We,
                               unsigned short* __restrict__ Wtn, unsigned short* __restrict__ Wte)
{
    int c = blockIdx.x * 256 + threadIdx.x;      // 0 .. 2*262144-1
    const int sel = c >> 18;
    const int idx = c & 262143;
    const int p = idx >> 9, k = idx & 511;
    const float* W = sel ? We : Wn;
    unsigned short* Wt = sel ? Wte : Wtn;
    Wt[((k >> 5) << 14) + (p << 5) + (k & 31)] = f2bf(W[(size_t)k * 512 + p]);
}

// --- Qp[b][p] = sum_k question[b][k]*Wq[k][p] + bq[p] + bh[p]  (atomic k-split)
__global__ void prep_q_kernel(const float* __restrict__ question,
                              const float* __restrict__ Wnq, const float* __restrict__ bnq,
                              const float* __restrict__ bn,
                              const float* __restrict__ Weq, const float* __restrict__ beq,
                              const float* __restrict__ be,
                              float* __restrict__ Qpn, float* __restrict__ Qpe)
{
    const int b     = blockIdx.x;    // 0..63
    const int which = blockIdx.y;    // 0=n 1=e
    const int kc    = blockIdx.z;    // 0..3 (chunks of 192)
    const int p     = threadIdx.x;   // 0..511
    const float* W  = which ? Weq : Wnq;
    const float* bq = which ? beq : bnq;
    const float* bh = which ? be  : bn;
    float* Qp       = which ? Qpe : Qpn;
    const float* q  = question + b * 768;
    float s = 0.f;
    const int kbeg = kc * 192, kend = kbeg + 192;
    for (int k = kbeg; k < kend; ++k) s += q[k] * W[(size_t)k * 512 + p];
    if (kc == 0) s += bq[p] + bh[p];
    atomicAdd(&Qp[b * 512 + p], s);
}

// --- main fused kernel -------------------------------------------------------
// grid.x = M/64, 512 threads (8 waves, 2x4 wave grid). Wave (wr,wc) owns rows
// [wr*32,+32) x cols [wc*128,+128) -> acc[2][8] 16x16 frags.
__global__ __launch_bounds__(512, 1)
void fused_gemm_attn(const float* __restrict__ A,          // [M][512] fp32
                     const unsigned short* __restrict__ Bt, // [16][512][32] bf16 tiled
                     const float* __restrict__ Qp,          // [64][512] fp32 (biases folded)
                     const float* __restrict__ wv,          // [512]
                     const float* __restrict__ bvp,         // scalar
                     const int*   __restrict__ gid,         // [M]
                     float* __restrict__ eout,              // [M]  exp(s) out
                     float* __restrict__ zglob)             // [64] segment sums
{
    __shared__ unsigned short Bs[3][512][BK];     // 96 KB triple-ring, linear
    __shared__ float sred[4][BM];
    __shared__ float zpart[64];
    __shared__ int   gsh[64];

    const int tid  = threadIdx.x;
    const int wave = tid >> 6;
    const int lane = tid & 63;
    const int m16  = lane & 15;
    const int q4   = lane >> 4;
    const int wr   = wave >> 2;     // 0..1
    const int wc   = wave & 3;      // 0..3
    const long r0  = (long)blockIdx.x * BM;

    // gid -> LDS; pinned BEFORE the DMA region so its compiler-inserted
    // vmcnt(0) (for the ds_write) drains only this load, keeping the manual
    // vmcnt ledger below exact.
    if (tid < 64) { gsh[tid] = gid[r0 + tid]; zpart[tid] = 0.f; }
    __builtin_amdgcn_sched_barrier(0);

    // B staging: 32KB window contiguous; 4 x 16B DMA per thread, linear dest
    const unsigned short* bsrc = Bt + (size_t)tid * 8;
    // A frag bases: lane (m16,q4) of wave (wr,*) reads rows wr*32+m16(+16),
    // k = t*32 + q4*8 .. +8  (8 consecutive fp32 = 2 float4)
    const float* aptr0 = A + (size_t)(r0 + wr * 32 + m16) * 512 + q4 * 8;
    const float* aptr1 = aptr0 + 16 * 512;

    floatx4 acc[2][8];
#pragma unroll
    for (int i = 0; i < 2; ++i)
#pragma unroll
        for (int j = 0; j < 8; ++j) acc[i][j] = (floatx4){0.f, 0.f, 0.f, 0.f};

    float4 apf[2][4];   // [slot][frag*2+half], statically indexed (full unroll)

    // ---- prologue: {B(0),A(0)}, {B(1),A(1)} in flight (16 VMEM) ----
#pragma unroll
    for (int i = 0; i < 4; ++i)
        gload16(bsrc + i * 4096, (char*)&Bs[0][0][0] + (tid + i * 512) * 16);
    apf[0][0] = *(const float4*)(aptr0);
    apf[0][1] = *(const float4*)(aptr0 + 4);
    apf[0][2] = *(const float4*)(aptr1);
    apf[0][3] = *(const float4*)(aptr1 + 4);
#pragma unroll
    for (int i = 0; i < 4; ++i)
        gload16(bsrc + 16384 + i * 4096, (char*)&Bs[1][0][0] + (tid + i * 512) * 16);
    apf[1][0] = *(const float4*)(aptr0 + 32);
    apf[1][1] = *(const float4*)(aptr0 + 36);
    apf[1][2] = *(const float4*)(aptr1 + 32);
    apf[1][3] = *(const float4*)(aptr1 + 36);

#pragma unroll
    for (int t = 0; t < NSTEP; ++t) {
        // certify tile t (its 8 VMEM from step t-2); keep tile t+1's 8 in flight
        if (t < NSTEP - 1) asm volatile("s_waitcnt vmcnt(8)" ::: "memory");
        else               asm volatile("s_waitcnt vmcnt(0)" ::: "memory");
        __builtin_amdgcn_s_barrier();       // all waves certified -> tile t visible

        // convert A(t) regs -> bf16 frags (frees apf[t&1] for reuse)
        shortx8 af[2];
#pragma unroll
        for (int i = 0; i < 2; ++i) {
            const float4 lo = apf[t & 1][i * 2];
            const float4 hi = apf[t & 1][i * 2 + 1];
            union { shortx8 v; unsigned u[4]; } r;
            r.u[0] = packbf(lo.x, lo.y);
            r.u[1] = packbf(lo.z, lo.w);
            r.u[2] = packbf(hi.x, hi.y);
            r.u[3] = packbf(hi.z, hi.w);
            af[i] = r.v;
        }

        // issue tile t+2: ring slot (t+2)%3 was last read in step t-1, whose
        // ds_reads completed before any wave passed this step's barrier.
        if (t + 2 < NSTEP) {
#pragma unroll
            for (int i = 0; i < 4; ++i)
                gload16(bsrc + (size_t)(t + 2) * 16384 + i * 4096,
                        (char*)&Bs[(t + 2) % 3][0][0] + (tid + i * 512) * 16);
            apf[t & 1][0] = *(const float4*)(aptr0 + (t + 2) * 32);
            apf[t & 1][1] = *(const float4*)(aptr0 + (t + 2) * 32 + 4);
            apf[t & 1][2] = *(const float4*)(aptr1 + (t + 2) * 32);
            apf[t & 1][3] = *(const float4*)(aptr1 + (t + 2) * 32 + 4);
        }

        // compute tile t: B frags from LDS ring, MFMA
#pragma unroll
        for (int j = 0; j < 8; ++j) {
            const shortx8 bfr = *(const shortx8*)&Bs[t % 3][wc * 128 + j * 16 + m16][q4 * 8];
#pragma unroll
            for (int i = 0; i < 2; ++i)
                acc[i][j] = __builtin_amdgcn_mfma_f32_16x16x32_bf16(af[i], bfr, acc[i][j], 0, 0, 0);
        }
        // no second barrier: next step's DMA targets a slot idle for 3 steps
    }

    // ---- epilogue: s[row] = sum_p tanh(h + Qp[g][p]) * wv[p] ----
    // C/D layout: col = lane&15, row = (lane>>4)*4 + reg   [verified m89/m91]
    const float bv = bvp[0];
    float wvp[8];
#pragma unroll
    for (int j = 0; j < 8; ++j) wvp[j] = wv[wc * 128 + j * 16 + m16];

#pragma unroll
    for (int i = 0; i < 2; ++i) {
#pragma unroll
        for (int reg = 0; reg < 4; ++reg) {
            const int row = wr * 32 + i * 16 + q4 * 4 + reg;
            const int g   = gsh[row];
            const float* qrow = Qp + (size_t)g * 512 + wc * 128 + m16;
            float partial = 0.f;
#pragma unroll
            for (int j = 0; j < 8; ++j) {
                float h  = acc[i][j][reg] + qrow[j * 16];
                float ex = __expf(2.f * h);                                // tanh
                float tt = (ex - 1.f) * __builtin_amdgcn_rcpf(ex + 1.f);
                partial += tt * wvp[j];
            }
            partial += __shfl_xor(partial, 1);
            partial += __shfl_xor(partial, 2);
            partial += __shfl_xor(partial, 4);
            partial += __shfl_xor(partial, 8);
            if (m16 == 0) sred[wc][row] = partial;   // per-colblock partial
        }
    }
    __syncthreads();
    if (tid < BM) {
        float s = bv + sred[0][tid] + sred[1][tid] + sred[2][tid] + sred[3][tid];
        float e = __expf(s);                       // no max-subtract: |s| small
        eout[r0 + tid] = e;
        atomicAdd(&zpart[gsh[tid]], e);
    }
    __syncthreads();
    if (tid < 64) {
        float v = zpart[tid];
        if (v != 0.f) atomicAdd(&zglob[tid], v);
    }
}

// --- normalize: att = e / z[gid] --------------------------------------------
__global__ void norm_kernel(float* __restrict__ out, const int* __restrict__ ngid,
                            const int* __restrict__ egid, const float* __restrict__ z)
{
    int idx = blockIdx.x * 256 + threadIdx.x;     // 0..393215
    float zz;
    if (idx < TN_CONST) zz = z[ngid[idx]];
    else                zz = z[64 + egid[idx - TN_CONST]];
    out[idx] = out[idx] / zz;
}

extern "C" void kernel_launch(void* const* d_in, const int* in_sizes, int n_in,
                              void* d_out, int out_size, void* d_ws, size_t ws_size,
                              hipStream_t stream)
{
    const float* question = (const float*)d_in[0];
    const float* nodes    = (const float*)d_in[1];
    const float* edges    = (const float*)d_in[2];
    const float* W_nq     = (const float*)d_in[3];
    const float* b_nq     = (const float*)d_in[4];
    const float* W_n      = (const float*)d_in[5];
    const float* b_n      = (const float*)d_in[6];
    const float* w_nv     = (const float*)d_in[7];
    const float* b_nv     = (const float*)d_in[8];
    const float* W_eq     = (const float*)d_in[9];
    const float* b_eq     = (const float*)d_in[10];
    const float* W_e      = (const float*)d_in[11];
    const float* b_e      = (const float*)d_in[12];
    const float* w_ev     = (const float*)d_in[13];
    const float* b_ev     = (const float*)d_in[14];
    const int* node_gid   = (const int*)d_in[15];
    const int* edge_gid   = (const int*)d_in[16];
    float* out = (float*)d_out;

    // workspace layout (bytes):
    //   [0,512)              z[128]
    //   [512,131584)         Qpn [64*512] f32
    //   [131584,262656)      Qpe [64*512] f32
    //   [262656,786944)      Wtn [512*512] bf16 (tiled)
    //   [786944,1311232)     Wte [512*512] bf16 (tiled)
    char* ws = (char*)d_ws;
    float*          z   = (float*)(ws);
    float*          Qpn = (float*)(ws + 512);
    float*          Qpe = (float*)(ws + 131584);
    unsigned short* Wtn = (unsigned short*)(ws + 262656);
    unsigned short* Wte = (unsigned short*)(ws + 786944);

    hipMemsetAsync(ws, 0, 262656, stream);  // z + Qpn + Qpe

    prep_wt_kernel<<<2048, 256, 0, stream>>>(W_n, W_e, Wtn, Wte);
    prep_q_kernel<<<dim3(64, 2, 4), 512, 0, stream>>>(question, W_nq, b_nq, b_n,
                                                      W_eq, b_eq, b_e, Qpn, Qpe);
    fused_gemm_attn<<<TN_CONST / BM, 512, 0, stream>>>(nodes, Wtn, Qpn, w_nv, b_nv,
                                                       node_gid, out, z);
    fused_gemm_attn<<<TE_CONST / BM, 512, 0, stream>>>(edges, Wte, Qpe, w_ev, b_ev,
                                                       edge_gid, out + TN_CONST, z + 64);
    norm_kernel<<<1536, 256, 0, stream>>>(out, node_gid, edge_gid, z);
}